// Round 3
// baseline (760.728 us; speedup 1.0000x reference)
//
#include <hip/hip_runtime.h>

// LabelSmoothing — R7: DIAGNOSTIC DOUBLE-PASS PROBE.
//
// R4/R5/R6 (row-block NT, row-block cached, flat sweep) all land at
// dur_us 629/658/645 while the harness's own 2GB fills run at 6.4 TB/s.
// Our kernel has NEVER appeared in the rocprof top-5 (always < the 5th
// ~322us fill), so we have never seen its true duration / FETCH_SIZE /
// occupancy, and we cannot distinguish "reads stuck at 1.7 TB/s" from
// "kernel hidden under harness fills".
//
// This version reads x TWICE (two identical sweep passes writing
// chunksumA/chunksumB; finish combines (A+B)*0.5 — bitwise exact since
// both passes produce identical fp sums, so absmax stays 0). The ~2x
// kernel is guaranteed to surface in the rocprof top-5 with its real
// counters. dur_us response discriminates serial-vs-overlapped timing:
//   serial+slow reads  -> dur ~950, kernel visible @~620, FETCH ~1.05GB
//   serial+amplified   -> kernel visible, FETCH >> 2GB
//   overlapped         -> dur ~650 unchanged, kernel visible @~620
//   serial+fast reads  -> dur ~500, kernel invisible (2 passes < 322us)

#define LS_V      32000
#define LS_V4     8000          // float4 per row
#define LS_SMOOTH 0.1f

#define SW_BLOCKS  2000
#define SW_THREADS 256
#define SW_TOTAL   (SW_BLOCKS * SW_THREADS)   // 512000 threads

typedef float f4 __attribute__((ext_vector_type(4)));

__global__ __launch_bounds__(SW_THREADS) void ls_sweep2(
    const float* __restrict__ x,
    float*       __restrict__ csA,    // one float per 64-f4 wave chunk
    float*       __restrict__ csB,
    int nf4)                          // N * 8000 (= 64 * SW_TOTAL exactly)
{
    const int g    = blockIdx.x * SW_THREADS + threadIdx.x;
    const int lane = threadIdx.x & 63;
    const f4* __restrict__ x4 = (const f4*)x;

    // PASS A — identical structure to R6's sweep.
    #pragma unroll 4
    for (int i = g; i < nf4; i += SW_TOTAL) {
        f4 v = __builtin_nontemporal_load(&x4[i]);
        float s = (v.x + v.y) + (v.z + v.w);
        #pragma unroll
        for (int off = 32; off > 0; off >>= 1)
            s += __shfl_down(s, off, 64);
        if (lane == 0) csA[i >> 6] = s;
    }

    // PASS B — bit-identical sequence over the same data.
    #pragma unroll 4
    for (int i = g; i < nf4; i += SW_TOTAL) {
        f4 v = __builtin_nontemporal_load(&x4[i]);
        float s = (v.x + v.y) + (v.z + v.w);
        #pragma unroll
        for (int off = 32; off > 0; off >>= 1)
            s += __shfl_down(s, off, 64);
        if (lane == 0) csB[i >> 6] = s;
    }
}

// One thread per row: combine 125 chunk sums (from both passes, averaged —
// exact since A==B bitwise) + gather term + mask.
__global__ __launch_bounds__(256) void ls_finish1(
    const float* __restrict__ x,
    const int*   __restrict__ target,
    const float* __restrict__ csA,
    const float* __restrict__ csB,
    float*       __restrict__ bsum)
{
    const int tid = threadIdx.x;
    const int r   = blockIdx.x * 256 + tid;

    const int   t = target[r];
    const float g = x[(size_t)r * LS_V + t];

    const int base = r * (LS_V4 / 64);          // 125 chunks per row
    float rs = 0.0f;
    #pragma unroll 5
    for (int i = 0; i < (LS_V4 / 64); ++i)
        rs += (csA[base + i] + csB[base + i]) * 0.5f;   // == csA[base+i] exactly

    float s = (t != 0) ? (-(LS_SMOOTH / (float)LS_V) * rs
                          - (1.0f - LS_SMOOTH) * g)
                       : 0.0f;

    #pragma unroll
    for (int off = 32; off > 0; off >>= 1)
        s += __shfl_down(s, off, 64);

    __shared__ float wsum[4];
    if ((tid & 63) == 0) wsum[tid >> 6] = s;
    __syncthreads();
    if (tid == 0)
        bsum[blockIdx.x] = (wsum[0] + wsum[1]) + (wsum[2] + wsum[3]);
}

__global__ __launch_bounds__(64) void ls_finish2(
    const float* __restrict__ bsum,
    float*       __restrict__ out,
    int nb)
{
    const int tid = threadIdx.x;
    float s = (tid < nb) ? bsum[tid] : 0.0f;
    #pragma unroll
    for (int off = 32; off > 0; off >>= 1)
        s += __shfl_down(s, off, 64);
    if (tid == 0) out[0] = s;
}

extern "C" void kernel_launch(void* const* d_in, const int* in_sizes, int n_in,
                              void* d_out, int out_size, void* d_ws, size_t ws_size,
                              hipStream_t stream)
{
    const float* x      = (const float*)d_in[0];   // [4096, 32000] fp32
    const int*   target = (const int*)d_in[1];     // [4096] int
    float*       out    = (float*)d_out;           // scalar fp32

    const int N    = in_sizes[1];                  // 4096 rows
    const int nf4  = N * LS_V4;                    // 32,768,000 float4
    const int nchk = nf4 >> 6;                     // 512,000 chunks

    float* csA  = (float*)d_ws;                    // 2 MB
    float* csB  = csA + nchk;                      // 2 MB
    float* bsum = csB + nchk;                      // 64 floats

    ls_sweep2 <<<SW_BLOCKS, SW_THREADS, 0, stream>>>(x, csA, csB, nf4);
    ls_finish1<<<N / 256,   256,        0, stream>>>(x, target, csA, csB, bsum);
    ls_finish2<<<1,         64,         0, stream>>>(bsum, out, N / 256);
}

// Round 5
// 638.899 us; speedup vs baseline: 1.1907x; 1.1907x over previous
//
#include <hip/hip_runtime.h>

// LabelSmoothing: x [N=4096, V=32000] fp32, target [N] int.
//   out = 0.1 * (-sum(x[valid rows])) / V + 0.9 * (-sum(x[i, target[i]], valid))
//
// R8 (resubmit — previous run died to an infra failure, not a kernel error).
// MIN-VALU SINGLE-PASS SWEEP.
// R7's double-pass probe established: reads run at ~4.5 TB/s marginal
// (+115.9us per extra 524MB pass) and the timed region carries ~529us of
// fixed harness cost (poison fills) we cannot touch. The only lever is the
// ~116us kernel chain, floor ~83us (524MB @ 6.3 TB/s).
//
// R6 spent ~13 instructions per 16B load (6 dependent shfl + conditional
// store per wave-chunk). This version spends 2 (NT load + f4 vector add):
//  - flat grid-stride sweep, 4096 blocks x 256, 4 independent f4
//    accumulators, ONE block+wave reduction at the very end.
//  - padding mask handled algebraically: S_valid = S_total - sum of rowsums
//    of masked rows (target==0, ~0-1 rows expected). Block b owns row b:
//    loads target[b] + gather x[b,t] at kernel start (latency hides under
//    the sweep); in the rare t==0 case the block re-streams its 128KB row
//    and folds the correction into the same block reduction.
//  - finish kernel: sum 4096 block partials (f4-vectorized, 1 block).

#define LS_V      32000
#define LS_V4     8000                 // float4 per row
#define LS_SMOOTH 0.1f

#define SB 4096                        // sweep blocks == N rows
#define ST 256                         // threads per block
#define STRIDE (SB * ST)               // 1,048,576 threads
#define NF4 (SB * LS_V4)               // 32,768,000 float4 total

typedef float f4 __attribute__((ext_vector_type(4)));

__global__ __launch_bounds__(ST) void ls_main(
    const float* __restrict__ x,
    const int*   __restrict__ target,
    float*       __restrict__ partial)
{
    const int tid = threadIdx.x;
    const int row = blockIdx.x;
    const int g   = row * ST + tid;
    const f4* __restrict__ x4 = (const f4*)x;

    // Early row-term loads: latency hides under the sweep.
    const int   t  = target[row];
    const float gv = x[(size_t)row * LS_V + t];

    // ---- flat sweep: 31.25 f4/thread (31 unconditional + 1 masked) ----
    f4 a0 = {0.f, 0.f, 0.f, 0.f};
    f4 a1 = a0, a2 = a0, a3 = a0;

    int i = g;
    #pragma unroll 1
    for (int k = 0; k < 7; ++k) {              // 7 x 4 = 28 iterations
        f4 v0 = __builtin_nontemporal_load(&x4[i]);
        f4 v1 = __builtin_nontemporal_load(&x4[i +     STRIDE]);
        f4 v2 = __builtin_nontemporal_load(&x4[i + 2 * STRIDE]);
        f4 v3 = __builtin_nontemporal_load(&x4[i + 3 * STRIDE]);
        a0 += v0; a1 += v1; a2 += v2; a3 += v3;
        i += 4 * STRIDE;
    }
    {                                           // iterations 28,29,30
        f4 v0 = __builtin_nontemporal_load(&x4[i]);
        f4 v1 = __builtin_nontemporal_load(&x4[i +     STRIDE]);
        f4 v2 = __builtin_nontemporal_load(&x4[i + 2 * STRIDE]);
        a0 += v0; a1 += v1; a2 += v2;
        i += 3 * STRIDE;
    }
    if (i < NF4) {                              // iteration 31: g < 262144 only
        a3 += __builtin_nontemporal_load(&x4[i]);
    }

    // ---- rare masked-row correction (block-uniform branch) ----
    // S_valid = S_total - rowsum(masked rows); fold -rowsum into this
    // block's reduction operand so ONE reduction handles both.
    if (t == 0) {
        const f4* __restrict__ xr = (const f4*)(x + (size_t)row * LS_V);
        f4 c = {0.f, 0.f, 0.f, 0.f};
        for (int j = tid; j < LS_V4; j += ST) c += xr[j];
        a0 -= c;
    }

    f4 av = ((a0 + a1) + (a2 + a3));
    float s = (av.x + av.y) + (av.z + av.w);

    #pragma unroll
    for (int off = 32; off > 0; off >>= 1)
        s += __shfl_down(s, off, 64);

    __shared__ float wsum[4];
    if ((tid & 63) == 0) wsum[tid >> 6] = s;
    __syncthreads();

    if (tid == 0) {
        const float U = (wsum[0] + wsum[1]) + (wsum[2] + wsum[3]);
        // partial[row] = smooth part of this block's sweep slice (masked-row
        // corrected) + this row's nll term (zero if padding row).
        float p = -(LS_SMOOTH / (float)LS_V) * U;
        if (t != 0) p -= (1.0f - LS_SMOOTH) * gv;
        partial[row] = p;
    }
}

__global__ __launch_bounds__(256) void ls_final(
    const float* __restrict__ partial,
    float*       __restrict__ out,
    int n)                                     // n = 4096
{
    const int tid = threadIdx.x;
    const int n4  = n >> 2;                    // 1024 float4
    const f4* __restrict__ p4 = (const f4*)partial;

    f4 acc = {0.f, 0.f, 0.f, 0.f};
    for (int i = tid; i < n4; i += 256) acc += p4[i];
    float s = (acc.x + acc.y) + (acc.z + acc.w);

    #pragma unroll
    for (int off = 32; off > 0; off >>= 1)
        s += __shfl_down(s, off, 64);

    __shared__ float wsum[4];
    if ((tid & 63) == 0) wsum[tid >> 6] = s;
    __syncthreads();
    if (tid == 0) out[0] = (wsum[0] + wsum[1]) + (wsum[2] + wsum[3]);
}

extern "C" void kernel_launch(void* const* d_in, const int* in_sizes, int n_in,
                              void* d_out, int out_size, void* d_ws, size_t ws_size,
                              hipStream_t stream)
{
    const float* x      = (const float*)d_in[0];   // [4096, 32000] fp32
    const int*   target = (const int*)d_in[1];     // [4096] int
    float*       out    = (float*)d_out;           // scalar fp32
    float*       part   = (float*)d_ws;            // 4096 fp32 partials

    const int N = in_sizes[1];                     // 4096 rows

    ls_main <<<N, ST,  0, stream>>>(x, target, part);
    ls_final<<<1, 256, 0, stream>>>(part, out, N);
}